// Round 2
// baseline (100.479 us; speedup 1.0000x reference)
//
#include <hip/hip_runtime.h>

// MeanAggregator: out[b,:] = (1/K) * sum_k features[idx[b,k],:]
// B=16384, K=15, U=19997, D=256 fp32.
//
// R5 post-mortem: R4 (2 rows/wave, fp16, 120 lines in flight) and R5
// (1 row/wave, SGPR-base gathers, 2-4x occupancy) both measured ~90 us --
// structure-insensitive => a fixed term dominates. rocprof top-5 is all
// __amd_rocclr_fillBufferAligned @ ~46 us, WRITE_SIZE = 256 MiB = the
// workspace re-poison, enqueued every timed iteration BECAUSE we use d_ws
// for the fp16 table. Neither of our kernels cracks the top-5 (<45.7 us
// each), so dur ~= 46 (poison) + ~40 (gather) + ~4 (cvt).
//
// R6: drop the workspace and the cvt stage entirely. Gather straight from
// the fp32 table: one output row per wave, lane l owns bytes [16l,16l+16)
// of the 1 KB row, 15 dwordx4 gathers with wave-uniform SGPR row bases
// (readlane), all 15 outstanding (60 dest VGPRs). Traffic doubles to
// ~250 MB but stays L3-resident and we are latency-bound with BW headroom
// (R4/R5 proved structure-insensitivity). Bonus: exact fp32 result.

#define K_NEIGH 15
#define D 256

__global__ __launch_bounds__(256, 6) void MeanAggregator_46024869544579_kernel(
    const int* __restrict__ idx,      // [B, K] int32
    const float4* __restrict__ feat,  // [U, D/4] fp32
    float4* __restrict__ out,         // [B, D/4]
    int B) {
  const int lane = threadIdx.x & 63;
  const int wave = blockIdx.x * 4 + (threadIdx.x >> 6);
  if (wave >= B) return;   // B=16384 -> exactly 16384 waves, no tail

  // Wave-uniform neighbor ids: lanes 0..14 load the row's 15 indices
  // (one dword load), then readlane -> SGPRs for scalar row bases.
  const int* rowidx = idx + (size_t)wave * K_NEIGH;
  int jl = rowidx[lane < K_NEIGH ? lane : 0];

  // 15 gathers, ALL outstanding before first use. Each instr: 64 lanes x
  // 16 B = one full 1 KB fp32 row = 8 x 128B lines; SGPR base per load,
  // shared lane voffset (lane*16), 60 dest VGPRs.
  float4 v[K_NEIGH];
#pragma unroll
  for (int t = 0; t < K_NEIGH; ++t) {
    int js = __builtin_amdgcn_readlane(jl, t);   // SGPR-uniform index
    v[t] = feat[(size_t)(unsigned)js * (D / 4) + lane];
  }

  float a0 = 0.f, a1 = 0.f, a2 = 0.f, a3 = 0.f;
#pragma unroll
  for (int t = 0; t < K_NEIGH; ++t) {
    a0 += v[t].x;
    a1 += v[t].y;
    a2 += v[t].z;
    a3 += v[t].w;
  }

  const float s = 1.0f / (float)K_NEIGH;
  float4 r;
  r.x = a0 * s; r.y = a1 * s; r.z = a2 * s; r.w = a3 * s;

  // lane holds elements [lane*4, lane*4+4): 1 KB contiguous store per wave.
  out[(size_t)wave * (D / 4) + lane] = r;
}

extern "C" void kernel_launch(void* const* d_in, const int* in_sizes, int n_in,
                              void* d_out, int out_size, void* d_ws, size_t ws_size,
                              hipStream_t stream) {
  const int* idx = (const int*)d_in[0];          // [B, K] int32
  const float4* feat = (const float4*)d_in[1];   // [U, D/4] fp32
  float4* out = (float4*)d_out;                  // [B, D/4]

  const int B = in_sizes[0] / K_NEIGH;           // 16384

  // No workspace use: no fp16 staging table, no 256 MiB re-poison cost,
  // single kernel launch.
  (void)d_ws; (void)ws_size;

  // 1 row per wave, 4 waves per block -> B/4 = 4096 blocks.
  const int grid = (B + 3) / 4;
  MeanAggregator_46024869544579_kernel<<<grid, 256, 0, stream>>>(idx, feat, out, B);
}

// Round 4
// 96.006 us; speedup vs baseline: 1.0466x; 1.0466x over previous
//
#include <hip/hip_runtime.h>
#include <hip/hip_fp16.h>

// MeanAggregator: out[b,:] = (1/K) * sum_k features[idx[b,k],:]
// B=16384, K=15, U=19997, D=256 fp32.
//
// R6 post-mortem: the 256 MiB fillBufferAligned re-poison is UNCONDITIONAL
// (persisted with d_ws unused) => fixed ~45 us term. fp32 gather cost +17 us
// over fp16 => bytes matter; back to fp16 staging.
//
// Gather plateau theory (R4/R5/R6 triangulation): ~39 us fp16 gather is
// insensitive to lines-in-flight/wave (120 vs 60), occupancy (2-4x), and
// instr count (123k vs 245k). Effective 3.2 TB/s == ~32 outstanding lines
// x 128 B / ~290 ns miss latency x 256 CU => per-CU TCP outstanding-miss
// queue is the ceiling, not wave-level concurrency. L1 hit rate ~0 for
// random 512B-row gathers from a 10 MB table, so L1 gives nothing and its
// miss queue throttles everything.
//
// R7 (rerun; prior attempt died to container-acquire infra failure):
// R5 structure + NONTEMPORAL (L1-bypass) gather loads. nt on idx load
// and cvt fp32 source too (zero reuse); nt-STORE on output (zero reuse,
// keeps L2 clean). cvt's fp16 table store stays CACHED (that's the hot
// data). Predict: gather 39 -> ~20 us, dur ~89.5 -> ~65-75.

#define K_NEIGH 15
#define D 256
#define ROW_U2 64   // 8B chunks per fp16 feature row (512 B)

typedef unsigned int v2u __attribute__((ext_vector_type(2)));
typedef unsigned int v4u __attribute__((ext_vector_type(4)));
typedef float v4f __attribute__((ext_vector_type(4)));

// fp32 -> fp16 table conversion: 8 floats per thread.
__global__ __launch_bounds__(256) void cvt_f32_to_f16(
    const v4f* __restrict__ src,  // [U*D/4]
    v4u* __restrict__ dst,        // [U*D/8]
    int n8) {
  int i = blockIdx.x * 256 + threadIdx.x;
  if (i >= n8) return;
  v4f v0 = __builtin_nontemporal_load(&src[2 * i]);      // streamed, no reuse
  v4f v1 = __builtin_nontemporal_load(&src[2 * i + 1]);
  __half2 a = __floats2half2_rn(v0.x, v0.y);
  __half2 b = __floats2half2_rn(v0.z, v0.w);
  __half2 c = __floats2half2_rn(v1.x, v1.y);
  __half2 d = __floats2half2_rn(v1.z, v1.w);
  v4u p;
  p.x = *reinterpret_cast<unsigned int*>(&a);
  p.y = *reinterpret_cast<unsigned int*>(&b);
  p.z = *reinterpret_cast<unsigned int*>(&c);
  p.w = *reinterpret_cast<unsigned int*>(&d);
  dst[i] = p;   // CACHED store: this is the table the gather re-reads 12x
}

__global__ __launch_bounds__(256, 8) void MeanAggregator_46024869544579_kernel(
    const int* __restrict__ idx,    // [B, K] int32
    const v2u* __restrict__ feat,   // [U, ROW_U2] fp16x4 packed
    v4f* __restrict__ out,          // [B, D/4]
    int B) {
  const int lane = threadIdx.x & 63;
  const int wave = blockIdx.x * 4 + (threadIdx.x >> 6);
  if (wave >= B) return;   // B=16384 -> exactly 16384 waves, no tail

  // Wave-uniform neighbor ids: lanes 0..14 load the row's 15 indices,
  // then readlane -> SGPRs for scalar row bases.
  const int* rowidx = idx + (size_t)wave * K_NEIGH;
  int jl = __builtin_nontemporal_load(&rowidx[lane < K_NEIGH ? lane : 0]);

  // 15 gathers, ALL outstanding before first use, L1-BYPASSED (nt):
  // each instr: 64 lanes x 8 B = one full 512 B fp16 row = 4 x 128B lines,
  // SGPR base + shared lane voffset. TCP miss queue no longer tracks them.
  v2u v[K_NEIGH];
#pragma unroll
  for (int t = 0; t < K_NEIGH; ++t) {
    int js = __builtin_amdgcn_readlane(jl, t);   // SGPR-uniform index
    v[t] = __builtin_nontemporal_load(&feat[(size_t)(unsigned)js * ROW_U2 + lane]);
  }

  float a0 = 0.f, a1 = 0.f, a2 = 0.f, a3 = 0.f;
#pragma unroll
  for (int t = 0; t < K_NEIGH; ++t) {
    unsigned int w0 = v[t].x, w1 = v[t].y;
    __half2 h0 = *reinterpret_cast<const __half2*>(&w0);
    __half2 h1 = *reinterpret_cast<const __half2*>(&w1);
    float2 f0 = __half22float2(h0);
    float2 f1 = __half22float2(h1);
    a0 += f0.x; a1 += f0.y; a2 += f1.x; a3 += f1.y;
  }

  const float s = 1.0f / (float)K_NEIGH;
  v4f r;
  r.x = a0 * s; r.y = a1 * s; r.z = a2 * s; r.w = a3 * s;

  // lane holds elements [lane*4, lane*4+4): 1 KB contiguous nt store.
  __builtin_nontemporal_store(r, &out[(size_t)wave * (D / 4) + lane]);
}

extern "C" void kernel_launch(void* const* d_in, const int* in_sizes, int n_in,
                              void* d_out, int out_size, void* d_ws, size_t ws_size,
                              hipStream_t stream) {
  const int* idx = (const int*)d_in[0];          // [B, K] int32
  const v4f* feat32 = (const v4f*)d_in[1];       // [U, D/4]
  v4f* out = (v4f*)d_out;                        // [B, D/4]

  const int B = in_sizes[0] / K_NEIGH;           // 16384
  const int n8 = in_sizes[1] / 8;                // U*D/8

  v4u* feat16 = (v4u*)d_ws;                      // 10.25 MB fp16 table

  cvt_f32_to_f16<<<(n8 + 255) / 256, 256, 0, stream>>>(feat32, feat16, n8);

  // 1 row per wave, 4 waves per block -> B/4 = 4096 blocks.
  const int grid = (B + 3) / 4;
  MeanAggregator_46024869544579_kernel<<<grid, 256, 0, stream>>>(
      idx, (const v2u*)feat16, out, B);
}

// Round 5
// 89.492 us; speedup vs baseline: 1.1228x; 1.0728x over previous
//
#include <hip/hip_runtime.h>
#include <hip/hip_fp16.h>

// MeanAggregator: out[b,:] = (1/K) * sum_k features[idx[b,k],:]
// B=16384, K=15, U=19997, D=256 fp32.
//
// Fixed decomposition (R4-R7): dur = fill(45.5, unconditional harness
// poison) + cvt(~5) + gather. fp16 gather plateau 39 us across R4/R5.
//
// R7 post-mortem: nt loads REGRESSED gather 39->46: nt also kills L2
// retention of the 12x-reused table => L1-bypass alone is worthless,
// L2 residency matters. All nt reverted.
//
// R8 experiment (single variable vs R5): maximize in-flight load-dest
// bytes per SIMD. R6 (fp32) is the only config >60 KB/SIMD in flight and
// the only one with better per-line cost (68.7 vs 97.5 cyc/line). Test:
// 4 output rows per wave = 60 outstanding dwordx2 gathers (vmcnt cap 63),
// 120 dest VGPRs, launch_bounds(256,3) => 3 waves/SIMD, 92 KB/SIMD in
// flight (1.5x R5), 720 lines/SIMD outstanding. SGPR-only addressing:
// 60 readlane indices, one shared lane voffset.
// Predict: if in-flight-bytes-bound, gather 39->~27, dur ~76-80;
// if memory-side small-burst floor, dur ~89-91 (null) => roofline case.

#define K_NEIGH 15
#define D 256
#define ROW_U2 64          // 8B chunks per fp16 feature row (512 B)
#define ROWS_PER_WAVE 4    // 60 gathers/wave, just under vmcnt=63 cap

typedef unsigned int v2u __attribute__((ext_vector_type(2)));
typedef unsigned int v4u __attribute__((ext_vector_type(4)));
typedef float v4f __attribute__((ext_vector_type(4)));

// fp32 -> fp16 table conversion: 8 floats per thread. (R5 version, no nt.)
__global__ __launch_bounds__(256) void cvt_f32_to_f16(
    const v4f* __restrict__ src,  // [U*D/4]
    v4u* __restrict__ dst,        // [U*D/8]
    int n8) {
  int i = blockIdx.x * 256 + threadIdx.x;
  if (i >= n8) return;
  v4f v0 = src[2 * i];
  v4f v1 = src[2 * i + 1];
  __half2 a = __floats2half2_rn(v0.x, v0.y);
  __half2 b = __floats2half2_rn(v0.z, v0.w);
  __half2 c = __floats2half2_rn(v1.x, v1.y);
  __half2 d = __floats2half2_rn(v1.z, v1.w);
  v4u p;
  p.x = *reinterpret_cast<unsigned int*>(&a);
  p.y = *reinterpret_cast<unsigned int*>(&b);
  p.z = *reinterpret_cast<unsigned int*>(&c);
  p.w = *reinterpret_cast<unsigned int*>(&d);
  dst[i] = p;
}

__global__ __launch_bounds__(256, 3) void MeanAggregator_46024869544579_kernel(
    const int* __restrict__ idx,    // [B, K] int32
    const v2u* __restrict__ feat,   // [U, ROW_U2] fp16x4 packed
    v4f* __restrict__ out,          // [B, D/4]
    int B) {
  const int lane = threadIdx.x & 63;
  const int wave = blockIdx.x * 4 + (threadIdx.x >> 6);
  const int row0 = wave * ROWS_PER_WAVE;
  if (row0 >= B) return;   // B=16384 -> exactly 4096 waves, no tail

  // 60 wave-uniform neighbor ids: lanes 0..59 load one each, then
  // readlane -> SGPR row bases at issue time (short scalar live ranges).
  const int* rowidx = idx + (size_t)row0 * K_NEIGH;
  int jl = rowidx[lane < ROWS_PER_WAVE * K_NEIGH ? lane : 0];

  // 60 gathers, ALL outstanding before first use. Each: 64 lanes x 8 B =
  // one full 512 B fp16 row = 4 lines. SGPR base + shared lane voffset.
  // Dest = 120 VGPRs committed while in flight.
  v2u v[ROWS_PER_WAVE * K_NEIGH];
#pragma unroll
  for (int t = 0; t < ROWS_PER_WAVE * K_NEIGH; ++t) {
    int js = __builtin_amdgcn_readlane(jl, t);   // SGPR-uniform index
    v[t] = feat[(size_t)(unsigned)js * ROW_U2 + lane];
  }

  // Consume in issue order (loads return in order; compiler emits
  // progressive vmcnt waits). All indices compile-time (full unroll).
  float a[ROWS_PER_WAVE][4];
#pragma unroll
  for (int r = 0; r < ROWS_PER_WAVE; ++r) {
    a[r][0] = 0.f; a[r][1] = 0.f; a[r][2] = 0.f; a[r][3] = 0.f;
  }

#pragma unroll
  for (int r = 0; r < ROWS_PER_WAVE; ++r) {
#pragma unroll
    for (int k = 0; k < K_NEIGH; ++k) {
      v2u w = v[r * K_NEIGH + k];
      unsigned int w0 = w.x, w1 = w.y;
      __half2 h0 = *reinterpret_cast<const __half2*>(&w0);
      __half2 h1 = *reinterpret_cast<const __half2*>(&w1);
      float2 f0 = __half22float2(h0);
      float2 f1 = __half22float2(h1);
      a[r][0] += f0.x; a[r][1] += f0.y; a[r][2] += f1.x; a[r][3] += f1.y;
    }
  }

  const float s = 1.0f / (float)K_NEIGH;
#pragma unroll
  for (int r = 0; r < ROWS_PER_WAVE; ++r) {
    v4f res;
    res.x = a[r][0] * s; res.y = a[r][1] * s;
    res.z = a[r][2] * s; res.w = a[r][3] * s;
    // lane holds elements [lane*4, lane*4+4) of row row0+r: contiguous 1 KB.
    out[(size_t)(row0 + r) * (D / 4) + lane] = res;
  }
}

extern "C" void kernel_launch(void* const* d_in, const int* in_sizes, int n_in,
                              void* d_out, int out_size, void* d_ws, size_t ws_size,
                              hipStream_t stream) {
  const int* idx = (const int*)d_in[0];          // [B, K] int32
  const v4f* feat32 = (const v4f*)d_in[1];       // [U, D/4]
  v4f* out = (v4f*)d_out;                        // [B, D/4]

  const int B = in_sizes[0] / K_NEIGH;           // 16384
  const int n8 = in_sizes[1] / 8;                // U*D/8

  v4u* feat16 = (v4u*)d_ws;                      // 10.25 MB fp16 table

  cvt_f32_to_f16<<<(n8 + 255) / 256, 256, 0, stream>>>(feat32, feat16, n8);

  // 4 rows per wave, 4 waves per block -> 16 rows/block, 1024 blocks.
  const int grid = (B + 15) / 16;
  MeanAggregator_46024869544579_kernel<<<grid, 256, 0, stream>>>(
      idx, (const v2u*)feat16, out, B);
}